// Round 3
// baseline (212.255 us; speedup 1.0000x reference)
//
#include <hip/hip_runtime.h>

// ANOVA kernel order 3:  out[b] = sum_e e3(x[b, :, e])
// x: (8192, 64, 64) fp32, row-major, e innermost.
//
// R3 = R2 kernel, launched TWICE (idempotent) as a designed measurement:
// bench dur = harness_overhead + 2*K. R2 gave overhead + K = 187.5 us.
// The delta vs R2 directly measures the kernel's own duration K, which
// rocprof top-5 can't show (buried under 80us ws-poison fills).
//
// One wave per batch row; lane = g + 16*h; g = float4 column group,
// h = field segment of 16. ESP DP per thread, segment-merge via
// e_k(A∪B) identity with shfl_xor(16,32), then sum-reduce over g.

constexpr int BATCH = 8192;

__device__ inline float4 shfl_xor4(float4 v, int d) {
    float4 r;
    r.x = __shfl_xor(v.x, d);
    r.y = __shfl_xor(v.y, d);
    r.z = __shfl_xor(v.z, d);
    r.w = __shfl_xor(v.w, d);
    return r;
}

__global__ __launch_bounds__(256) void anova3_kernel(const float* __restrict__ x,
                                                     float* __restrict__ out) {
    const int tid  = blockIdx.x * 256 + threadIdx.x;
    const int lane = threadIdx.x & 63;
    const int b    = tid >> 6;        // one wave per batch row
    const int g    = lane & 15;       // float4 group within 64-wide embedding
    const int h    = lane >> 4;       // field segment [0,4)

    const float4* xp = reinterpret_cast<const float4*>(x)
                     + (size_t)b * 1024 + (size_t)h * 256 + g;

    float4 s1 = make_float4(0.f, 0.f, 0.f, 0.f);
    float4 s2 = s1, s3 = s1;

#pragma unroll
    for (int f = 0; f < 16; ++f) {
        float4 v = xp[f * 16];
        s3.x = fmaf(s2.x, v.x, s3.x); s2.x = fmaf(s1.x, v.x, s2.x); s1.x += v.x;
        s3.y = fmaf(s2.y, v.y, s3.y); s2.y = fmaf(s1.y, v.y, s2.y); s1.y += v.y;
        s3.z = fmaf(s2.z, v.z, s3.z); s2.z = fmaf(s1.z, v.z, s2.z); s1.z += v.z;
        s3.w = fmaf(s2.w, v.w, s3.w); s2.w = fmaf(s1.w, v.w, s2.w); s1.w += v.w;
    }

#pragma unroll
    for (int d = 16; d <= 32; d <<= 1) {
        float4 o1 = shfl_xor4(s1, d);
        float4 o2 = shfl_xor4(s2, d);
        float4 o3 = shfl_xor4(s3, d);
        s3.x += o3.x + s2.x * o1.x + s1.x * o2.x;
        s3.y += o3.y + s2.y * o1.y + s1.y * o2.y;
        s3.z += o3.z + s2.z * o1.z + s1.z * o2.z;
        s3.w += o3.w + s2.w * o1.w + s1.w * o2.w;
        s2.x += o2.x + s1.x * o1.x;
        s2.y += o2.y + s1.y * o1.y;
        s2.z += o2.z + s1.z * o1.z;
        s2.w += o2.w + s1.w * o1.w;
        s1.x += o1.x; s1.y += o1.y; s1.z += o1.z; s1.w += o1.w;
    }

    float r = (s3.x + s3.y) + (s3.z + s3.w);
    r += __shfl_xor(r, 1);
    r += __shfl_xor(r, 2);
    r += __shfl_xor(r, 4);
    r += __shfl_xor(r, 8);

    if (lane == 0) out[b] = r;
}

extern "C" void kernel_launch(void* const* d_in, const int* in_sizes, int n_in,
                              void* d_out, int out_size, void* d_ws, size_t ws_size,
                              hipStream_t stream) {
    const float* x = (const float*)d_in[0];
    float* out = (float*)d_out;
    const int total_threads = BATCH * 64;   // one wave per row
    dim3 grid(total_threads / 256);         // 2048 blocks
    // Launched twice on purpose (measurement round): dur = OH + 2K.
    anova3_kernel<<<grid, dim3(256), 0, stream>>>(x, out);
    anova3_kernel<<<grid, dim3(256), 0, stream>>>(x, out);
}

// Round 4
// 184.647 us; speedup vs baseline: 1.1495x; 1.1495x over previous
//
#include <hip/hip_runtime.h>

// ANOVA kernel order 3:  out[b] = sum_e e3(x[b, :, e])
// x: (8192, 64, 64) fp32, row-major, e innermost.
//
// R4: one wave per batch row; every wave-wide load is a fully contiguous,
// 1 KB-aligned span (unit = i*64 + lane of the row's 1024 float4 units).
// Thread (lane) therefore owns fields {4i + (lane>>4)} for embedding column
// group g = lane&15 — a stride-4 field subsequence. ESP is subset-agnostic:
// the e_k(A∪B) merge identity over h = lane>>4 (shfl_xor 16, 32) is unchanged,
// then e3 is summed over components and over g (shfl_xor 1,2,4,8).
//
// Measured R3: kernel K = 24.75 us (5.42 TB/s); harness fixed overhead
// ~162.7 us. This round targets the last ~16% vs the ~6.3 TB/s read ceiling.

constexpr int BATCH = 8192;

__device__ inline float4 shfl_xor4(float4 v, int d) {
    float4 r;
    r.x = __shfl_xor(v.x, d);
    r.y = __shfl_xor(v.y, d);
    r.z = __shfl_xor(v.z, d);
    r.w = __shfl_xor(v.w, d);
    return r;
}

__global__ __launch_bounds__(256) void anova3_kernel(const float* __restrict__ x,
                                                     float* __restrict__ out) {
    const int tid  = blockIdx.x * 256 + threadIdx.x;
    const int lane = threadIdx.x & 63;
    const int b    = tid >> 6;        // one wave per batch row

    // Row = 1024 float4 units. Load i covers units [i*64, (i+1)*64): 1 KB contiguous.
    const float4* xp = reinterpret_cast<const float4*>(x)
                     + (size_t)b * 1024 + lane;

    float4 s1 = make_float4(0.f, 0.f, 0.f, 0.f);
    float4 s2 = s1, s3 = s1;

#pragma unroll
    for (int i = 0; i < 16; ++i) {
        float4 v = xp[i * 64];
        // ESP DP; order matters: s3 uses old s2, s2 uses old s1
        s3.x = fmaf(s2.x, v.x, s3.x); s2.x = fmaf(s1.x, v.x, s2.x); s1.x += v.x;
        s3.y = fmaf(s2.y, v.y, s3.y); s2.y = fmaf(s1.y, v.y, s2.y); s1.y += v.y;
        s3.z = fmaf(s2.z, v.z, s3.z); s2.z = fmaf(s1.z, v.z, s2.z); s1.z += v.z;
        s3.w = fmaf(s2.w, v.w, s3.w); s2.w = fmaf(s1.w, v.w, s2.w); s1.w += v.w;
    }

    // Merge the 4 disjoint field subsets across h = lane>>4.
#pragma unroll
    for (int d = 16; d <= 32; d <<= 1) {
        float4 o1 = shfl_xor4(s1, d);
        float4 o2 = shfl_xor4(s2, d);
        float4 o3 = shfl_xor4(s3, d);
        s3.x += o3.x + s2.x * o1.x + s1.x * o2.x;
        s3.y += o3.y + s2.y * o1.y + s1.y * o2.y;
        s3.z += o3.z + s2.z * o1.z + s1.z * o2.z;
        s3.w += o3.w + s2.w * o1.w + s1.w * o2.w;
        s2.x += o2.x + s1.x * o1.x;
        s2.y += o2.y + s1.y * o1.y;
        s2.z += o2.z + s1.z * o1.z;
        s2.w += o2.w + s1.w * o1.w;
        s1.x += o1.x; s1.y += o1.y; s1.z += o1.z; s1.w += o1.w;
    }

    // Sum e3 over components and over the 16 g-groups (lane bits 0..3).
    float r = (s3.x + s3.y) + (s3.z + s3.w);
    r += __shfl_xor(r, 1);
    r += __shfl_xor(r, 2);
    r += __shfl_xor(r, 4);
    r += __shfl_xor(r, 8);

    if (lane == 0) out[b] = r;
}

extern "C" void kernel_launch(void* const* d_in, const int* in_sizes, int n_in,
                              void* d_out, int out_size, void* d_ws, size_t ws_size,
                              hipStream_t stream) {
    const float* x = (const float*)d_in[0];
    float* out = (float*)d_out;
    const int total_threads = BATCH * 64;   // one wave per row
    dim3 grid(total_threads / 256);         // 2048 blocks
    anova3_kernel<<<grid, dim3(256), 0, stream>>>(x, out);
}